// Round 19
// baseline (281.173 us; speedup 1.0000x reference)
//
#include <hip/hip_runtime.h>
#include <stdint.h>
#include <stddef.h>

typedef unsigned short u16;
typedef short bf16x8 __attribute__((ext_vector_type(8)));
typedef float f32x4 __attribute__((ext_vector_type(4)));
typedef float f32x16 __attribute__((ext_vector_type(16)));
typedef unsigned short ushort8v __attribute__((ext_vector_type(8)));
typedef int i32x2 __attribute__((ext_vector_type(2)));

#define LR 2048
#define LOG2E 1.44269504088896f

__device__ __forceinline__ u16 f2bf(float f) {
  unsigned u = __float_as_uint(f);
  unsigned r = u + 0x7fffu + ((u >> 16) & 1u);
  return (u16)(r >> 16);
}

__device__ __forceinline__ unsigned cvtpk(float lo, float hi) {
  unsigned r;
  asm("v_cvt_pk_bf16_f32 %0, %1, %2" : "=v"(r) : "v"(lo), "v"(hi));
  return r;
}

// v_permlane32_swap: vdst[32:63] <-> vsrc[0:31]
__device__ __forceinline__ void plswap(unsigned& a, unsigned& b) {
#if __has_builtin(__builtin_amdgcn_permlane32_swap)
  i32x2 r = __builtin_amdgcn_permlane32_swap((int)a, (int)b, false, false);
  a = (unsigned)r[0];
  b = (unsigned)r[1];
#else
  asm volatile("s_nop 1\n\tv_permlane32_swap_b32 %0, %1\n\ts_nop 1"
               : "+v"(a), "+v"(b));
#endif
}
__device__ __forceinline__ float xhalf_sum(float x) {
  unsigned a = __float_as_uint(x), b = __float_as_uint(x);
  plswap(a, b);
  return __uint_as_float(a) + __uint_as_float(b);
}

__device__ __forceinline__ void gl_lds16(const void* g, void* l) {
  __builtin_amdgcn_global_load_lds((__attribute__((address_space(1))) void*)g,
                                   (__attribute__((address_space(3))) void*)l,
                                   16, 0, 0);
}

// Closed-form Hilbert perm for this problem's segments (inlined, no kernel)
__device__ __forceinline__ int hilbert_perm(int idx) {
  int seg = (idx < 2048) ? 0 : (idx < 6144 ? 1 : 2);
  int segpos = (seg == 0) ? 0 : (seg == 1 ? 2048 : 6144);
  int L = 2048 << seg;
  int n = (seg == 2) ? 128 : 64;
  int t = idx - segpos;
  int d = (L == n * n) ? t : ((t < (L >> 1)) ? t : t + L);
  int x = 0, y = 0;
  for (int s = 1; s < n; s <<= 1) {
    int rx = 1 & (d >> 1);
    int ry = 1 & (d ^ rx);
    if (ry == 0) {
      if (rx == 1) { x = s - 1 - x; y = s - 1 - y; }
      int tmp = x; x = y; y = tmp;
    }
    x += s * rx; y += s * ry;
    d >>= 2;
  }
  return y * n + x;
}

// ---------------- fused weight transpose + convert (wqkv + wo in one launch) -
__global__ void wtrans_kernel(const float* __restrict__ q0, const float* __restrict__ q1,
                              const float* __restrict__ q2, const float* __restrict__ o0,
                              const float* __restrict__ o1, const float* __restrict__ o2,
                              u16* __restrict__ dq, u16* __restrict__ dw) {
  const int seg = blockIdx.z;
  const int bx = blockIdx.x;
  const int K = 1024;
  int tx = threadIdx.x, ty = threadIdx.y;  // (32,8)
  __shared__ float tl[32][33];
  const float* S;
  u16* D;
  int N, n0, do_remap;
  if (bx < 96) {
    S = (seg == 0) ? q0 : (seg == 1 ? q1 : q2);
    D = dq + (size_t)seg * K * 3072;
    N = 3072; n0 = bx * 32; do_remap = 0;
  } else {
    S = (seg == 0) ? o0 : (seg == 1 ? o1 : o2);
    D = dw + (size_t)seg * K * 1024;
    N = 1024; n0 = (bx - 96) * 32; do_remap = 1;
  }
  int k0 = blockIdx.y * 32;
  #pragma unroll
  for (int i = 0; i < 4; i++)
    tl[ty + 8 * i][tx] = S[(size_t)(k0 + ty + 8 * i) * N + n0 + tx];
  __syncthreads();
  int kk = k0 + tx;
  if (do_remap) {
    int rate = 1 << seg;
    int h = kk >> 6;
    int h2 = (h & (rate - 1)) * (16 >> seg) + (h >> seg);
    kk = h2 * 64 + (kk & 63);
  }
  #pragma unroll
  for (int i = 0; i < 4; i++)
    D[(size_t)(n0 + ty + 8 * i) * K + kk] = f2bf(tl[tx][ty + 8 * i]);
}

// ---------------- gather x rows: inline hilbert + dilation reorder, f32->bf16
__global__ void gather_kernel(const float* __restrict__ x, u16* __restrict__ xh) {
  int rr = blockIdx.x;
  int seg = (rr < 2048) ? 0 : (rr < 6144 ? 1 : 2);
  int segpos = (seg == 0) ? 0 : (seg == 1 ? 2048 : 6144);
  int rate = 1 << seg;
  int rl = rr - segpos;
  int t = (rl & (LR - 1)) * rate + (rl >> 11);
  int orig = segpos + hilbert_perm(segpos + t);
  float4 v = *((const float4*)(x + (size_t)orig * 1024) + threadIdx.x);
  ushort4 o;
  o.x = f2bf(v.x); o.y = f2bf(v.y); o.z = f2bf(v.z); o.w = f2bf(v.w);
  *((ushort4*)(xh + (size_t)rr * 1024) + threadIdx.x) = o;
}

// ---------------- QKV GEMM (R14-exact): 256x256 tile, 8 waves, BK=64, -------
// 128KB LDS dbuf, stage-early + single __syncthreads per K-step, XCD supertile.
__global__ __launch_bounds__(512, 2) void qkv_gemm_kernel(
    const u16* __restrict__ A, const u16* __restrict__ Bt,
    const float* __restrict__ b0, const float* __restrict__ b1,
    const float* __restrict__ b2, u16* __restrict__ C) {
  __shared__ char smem[131072];
  const int tid = threadIdx.x;
  const int lane = tid & 63, wid = tid >> 6;   // 8 waves
  const int wm = wid >> 2, wn = wid & 3;       // 2m x 4n, wave tile 128x64
  const int bid = blockIdx.x;                  // 672 = 8 xcd * (2 grp * 7 rb * 6 nb)
  const int xcd = bid & 7;
  const int idx = bid >> 3;
  const int grp = idx / 42;
  const int rem = idx % 42;
  const int rb = xcd * 7 + rem / 6;
  const int nb = grp * 6 + rem % 6;
  const int seg = (rb < 8) ? 0 : (rb < 24 ? 1 : 2);
  const float* bias = (seg == 0) ? b0 : (seg == 1 ? b1 : b2);
  const size_t arow0 = (size_t)rb * 256;
  const char* Ab = (const char*)(A + arow0 * 1024);
  const char* Bb = (const char*)(Bt + ((size_t)seg * 3072 + (size_t)nb * 256) * 1024);

  f32x4 acc[8][4] = {};

  #pragma unroll
  for (int it = 0; it < 4; it++) {
    int p = (it * 512 + tid) * 16;
    int e = p ^ (((p >> 7) & 7) << 4);
    int row = e >> 7, col = e & 127;
    gl_lds16(Ab + (size_t)row * 2048 + col, smem + it * 8192 + wid * 1024);
    gl_lds16(Bb + (size_t)row * 2048 + col, smem + 65536 + it * 8192 + wid * 1024);
  }
  __syncthreads();

  for (int kt = 0; kt < 16; kt++) {
    const int buf = kt & 1, nbuf = buf ^ 1;
    char* As = smem + buf * 32768;
    char* Bs = smem + 65536 + buf * 32768;
    if (kt < 15) {
      #pragma unroll
      for (int it = 0; it < 4; it++) {
        int p = (it * 512 + tid) * 16;
        int e = p ^ (((p >> 7) & 7) << 4);
        int row = e >> 7, col = e & 127;
        gl_lds16(Ab + (size_t)row * 2048 + (kt + 1) * 128 + col,
                 smem + nbuf * 32768 + it * 8192 + wid * 1024);
        gl_lds16(Bb + (size_t)row * 2048 + (kt + 1) * 128 + col,
                 smem + 65536 + nbuf * 32768 + it * 8192 + wid * 1024);
      }
    }
    #pragma unroll
    for (int kc = 0; kc < 2; kc++) {
      bf16x8 af[8], bfr[4];
      #pragma unroll
      for (int m = 0; m < 8; m++) {
        int row = wm * 128 + m * 16 + (lane & 15);
        int e = row * 128 + kc * 64 + ((lane >> 4) << 4);
        af[m] = *(const bf16x8*)(As + (e ^ ((row & 7) << 4)));
      }
      #pragma unroll
      for (int n = 0; n < 4; n++) {
        int row = wn * 64 + n * 16 + (lane & 15);
        int e = row * 128 + kc * 64 + ((lane >> 4) << 4);
        bfr[n] = *(const bf16x8*)(Bs + (e ^ ((row & 7) << 4)));
      }
      #pragma unroll
      for (int m = 0; m < 8; m++)
        #pragma unroll
        for (int n = 0; n < 4; n++)
          acc[m][n] = __builtin_amdgcn_mfma_f32_16x16x32_bf16(af[m], bfr[n], acc[m][n], 0, 0, 0);
    }
    __syncthreads();
  }

  float bv[4];
  #pragma unroll
  for (int n = 0; n < 4; n++) bv[n] = bias[nb * 256 + wn * 64 + n * 16 + (lane & 15)];
  #pragma unroll
  for (int pass = 0; pass < 2; pass++) {
    if (wm == pass) {
      #pragma unroll
      for (int m = 0; m < 8; m++)
        #pragma unroll
        for (int n = 0; n < 4; n++)
          #pragma unroll
          for (int j = 0; j < 4; j++) {
            int r = m * 16 + ((lane >> 4) << 2) + j;
            int c = wn * 64 + n * 16 + (lane & 15);
            *(u16*)(smem + r * 528 + c * 2) = f2bf(acc[m][n][j] + bv[n]);
          }
    }
    __syncthreads();
    #pragma unroll
    for (int it = 0; it < 8; it++) {
      int ci = it * 512 + tid;
      int row = ci >> 5, c16 = ci & 31;
      bf16x8 vv = *(const bf16x8*)(smem + row * 528 + c16 * 16);
      u16* crow = C + (arow0 + pass * 128 + row) * 3072 + nb * 256;
      *(bf16x8*)((char*)crow + c16 * 16) = vv;
    }
    if (pass == 0) __syncthreads();
  }
}

// ---------------- flash attention v9: QBLK=256 (8 waves, 512 thr) ------------
// Halves K/V panel traffic (8 q-blocks per (seg,h) instead of 16); per-wave
// work unchanged; 16 waves/CU. K stage = 1 gl_lds/thread; V on waves 0-3.
__global__ __launch_bounds__(512, 4) void attn_kernel(const u16* __restrict__ qkv,
                                                      u16* __restrict__ opre) {
  __shared__ char smem[32768];
  const int tid = threadIdx.x;          // 0..511
  const int lane = tid & 63;
  const int wid = tid >> 6;             // 0..7
  const int l31 = lane & 31;
  const int hi = lane >> 5;
  const int by = blockIdx.y;
  const int seg = by >> 4, h = by & 15;
  const int segrow = (seg == 0) ? 0 : (seg == 1 ? 2048 : 6144);
  const int rate = 1 << seg;
  const int off = h & (rate - 1);
  const int base = segrow + off * LR;
  const int h_col = off * (16 >> seg) + (h >> seg);
  const int q0 = blockIdx.x * 256;
  const int qw = q0 + wid * 32;
  const char* qb = (const char*)qkv;

  // V transpose mapping (block-cooperative, waves 0-3): 2 keys x 8 d each
  const bool vact = (tid < 256);
  const int vkey0 = 2 * (tid & 31);
  const int vd0 = ((tid & 255) >> 5) * 8;

  // ---- prologue: stage K0 (1 gl_lds/thread), V0 regs, Q frags ----
  {
    int p = tid * 16;
    int e = p ^ (((p >> 7) & 7) << 4);
    int row = e >> 7, col = e & 127;
    gl_lds16(qb + (size_t)(base + row) * 6144 + 2048 + h * 128 + col,
             smem + wid * 1024);
  }
  ushort8v v0r = {}, v1r = {};
  if (vact) {
    v0r = *(const ushort8v*)(qb + (size_t)(base + vkey0) * 6144 + 4096 + h * 128 + vd0 * 2);
    v1r = *(const ushort8v*)(qb + (size_t)(base + vkey0 + 1) * 6144 + 4096 + h * 128 + vd0 * 2);
  }
  bf16x8 qf[4];
  #pragma unroll
  for (int i2 = 0; i2 < 4; i2++)
    qf[i2] = *(const bf16x8*)(qb + (size_t)(base + qw + l31) * 6144 + h * 128 + i2 * 32 + hi * 16);
  if (vact) {
    #pragma unroll
    for (int dd = 0; dd < 8; dd++) {
      int d = vd0 + dd;
      unsigned val = (unsigned)(u16)v0r[dd] | ((unsigned)(u16)v1r[dd] << 16);
      int addr = d * 128 + vkey0 * 2;
      *(unsigned*)(smem + 16384 + (addr ^ ((d & 7) << 4))) = val;
    }
  }
  __syncthreads();

  float Lrun = 0.f;
  f32x16 accO0 = {}, accO1 = {};
  const float K1 = 0.125f * LOG2E;
  const float C2 = 4.0f * LOG2E;

  for (int kt = 0; kt < 32; kt++) {
    const int cur = kt & 1;
    const int nxt = cur ^ 1;
    char* Ks  = smem + (cur << 13);
    char* Vt  = smem + 16384 + (cur << 13);
    char* Ksn = smem + (nxt << 13);
    char* Vtn = smem + 16384 + (nxt << 13);
    ushort8v nv0 = {}, nv1 = {};
    if (kt < 31) {
      {
        int p = tid * 16;
        int e = p ^ (((p >> 7) & 7) << 4);
        int row = e >> 7, col = e & 127;
        gl_lds16(qb + (size_t)(base + (kt + 1) * 64 + row) * 6144 + 2048 + h * 128 + col,
                 Ksn + wid * 1024);
      }
      if (vact) {
        nv0 = *(const ushort8v*)(qb + (size_t)(base + (kt + 1) * 64 + vkey0) * 6144 + 4096 + h * 128 + vd0 * 2);
        nv1 = *(const ushort8v*)(qb + (size_t)(base + (kt + 1) * 64 + vkey0 + 1) * 6144 + 4096 + h * 128 + vd0 * 2);
      }
    }
    #pragma unroll
    for (int s = 0; s < 2; s++) {
      f32x16 sacc = {};
      __builtin_amdgcn_s_setprio(1);
      #pragma unroll
      for (int i2 = 0; i2 < 4; i2++) {
        int row = s * 32 + l31;
        int addr = (row * 128 + i2 * 32 + hi * 16) ^ ((row & 7) << 4);
        bf16x8 kf = *(const bf16x8*)(Ks + addr);
        sacc = __builtin_amdgcn_mfma_f32_32x32x16_bf16(kf, qf[i2], sacc, 0, 0, 0);
      }
      __builtin_amdgcn_s_setprio(0);
      #pragma unroll
      for (int r = 0; r < 16; r++) sacc[r] = exp2f(sacc[r] * K1 - C2);
      float s8[8];
      #pragma unroll
      for (int t = 0; t < 8; t++) s8[t] = sacc[2 * t] + sacc[2 * t + 1];
      float sm = (((s8[0] + s8[1]) + (s8[2] + s8[3])) + ((s8[4] + s8[5]) + (s8[6] + s8[7])));
      Lrun += xhalf_sum(sm);
      unsigned w[8];
      #pragma unroll
      for (int t = 0; t < 8; t++) w[t] = cvtpk(sacc[2 * t], sacc[2 * t + 1]);
      plswap(w[0], w[2]); plswap(w[1], w[3]);
      plswap(w[4], w[6]); plswap(w[5], w[7]);
      union PU { unsigned u[4]; bf16x8 v; };
      PU pu0, pu1;
      pu0.u[0] = w[0]; pu0.u[1] = w[1]; pu0.u[2] = w[2]; pu0.u[3] = w[3];
      pu1.u[0] = w[4]; pu1.u[1] = w[5]; pu1.u[2] = w[6]; pu1.u[3] = w[7];
      __builtin_amdgcn_s_setprio(1);
      #pragma unroll
      for (int j = 0; j < 2; j++) {
        bf16x8 pa = (j == 0) ? pu0.v : pu1.v;
        #pragma unroll
        for (int dt = 0; dt < 2; dt++) {
          int d = dt * 32 + l31;
          int addr = (d * 128 + s * 64 + j * 32 + hi * 16) ^ ((d & 7) << 4);
          bf16x8 vf = *(const bf16x8*)(Vt + addr);
          if (dt == 0) accO0 = __builtin_amdgcn_mfma_f32_32x32x16_bf16(pa, vf, accO0, 0, 0, 0);
          else         accO1 = __builtin_amdgcn_mfma_f32_32x32x16_bf16(pa, vf, accO1, 0, 0, 0);
        }
      }
      __builtin_amdgcn_s_setprio(0);
    }
    if (kt < 31 && vact) {
      #pragma unroll
      for (int dd = 0; dd < 8; dd++) {
        int d = vd0 + dd;
        unsigned val = (unsigned)(u16)nv0[dd] | ((unsigned)(u16)nv1[dd] << 16);
        int addr = d * 128 + vkey0 * 2;
        *(unsigned*)(Vtn + (addr ^ ((d & 7) << 4))) = val;
      }
    }
    __syncthreads();
  }

  // ---- epilogue: O -> LDS (32KB bounce) -> global ----
  float invL = 1.0f / Lrun;
  #pragma unroll
  for (int r = 0; r < 16; r++) {
    int qrow = (r & 3) + 8 * (r >> 2) + 4 * hi;
    float li = __shfl(invL, qrow);
    int qloc = wid * 32 + qrow;                 // 0..255
    int a0 = (qloc * 128 + l31 * 2) ^ ((qrow & 7) << 4);
    int a1 = (qloc * 128 + 64 + l31 * 2) ^ ((qrow & 7) << 4);
    *(u16*)(smem + a0) = f2bf(accO0[r] * li);
    *(u16*)(smem + a1) = f2bf(accO1[r] * li);
  }
  __syncthreads();
  #pragma unroll
  for (int it = 0; it < 4; it++) {
    int idx = it * 512 + tid;
    int row = idx >> 3, c16 = idx & 7;          // 256 rows x 8 chunks
    int a = (row * 128 + c16 * 16) ^ ((row & 7) << 4);
    bf16x8 vv = *(const bf16x8*)(smem + a);
    *(bf16x8*)((char*)(opre + (size_t)(base + q0 + row) * 1024 + h_col * 64) + c16 * 16) = vv;
  }
}

// ---------------- OUT GEMM (2-phase dbuf): residue-sparse x Wo^T -> f32 ------
__global__ __launch_bounds__(256) void out_gemm_kernel(
    const u16* __restrict__ A, const u16* __restrict__ Bt,
    const float* __restrict__ b0, const float* __restrict__ b1,
    const float* __restrict__ b2, float* __restrict__ Out) {
  __shared__ char smem[65536];
  __shared__ int drow[128];
  const int tid = threadIdx.x;
  const int lane = tid & 63, wid = tid >> 6;
  const int wm = wid >> 1, wn = wid & 1;
  const int rb = blockIdx.x, nb = blockIdx.y;
  const int seg = (rb < 16) ? 0 : (rb < 48 ? 1 : 2);
  const int segpos = (seg == 0) ? 0 : (seg == 1 ? 2048 : 6144);
  const int rate = 1 << seg;
  const float* bias = (seg == 0) ? b0 : (seg == 1 ? b1 : b2);
  const size_t arow0 = (size_t)rb * 128;
  const char* Ab = (const char*)(A + arow0 * 1024);
  const char* Bb = (const char*)(Bt + ((size_t)seg * 1024 + (size_t)nb * 128) * 1024);

  const int blk = (int)(arow0 - segpos) >> 11;
  const int ktpb = 16 >> seg;
  const int kt0 = blk * ktpb;

  f32x4 acc[4][4] = {};

  if (tid < 128) {
    int rl = (int)arow0 + tid - segpos;
    int t = (rl & (LR - 1)) * rate + (rl >> 11);
    drow[tid] = segpos + hilbert_perm(segpos + t);
  }

  #pragma unroll
  for (int it = 0; it < 4; it++) {
    int p = (it * 256 + tid) * 16;
    int e = p ^ (((p >> 7) & 7) << 4);
    int row = e >> 7, col = e & 127;
    gl_lds16(Ab + (size_t)row * 2048 + kt0 * 128 + col, smem + it * 4096 + wid * 1024);
    gl_lds16(Bb + (size_t)row * 2048 + kt0 * 128 + col, smem + 32768 + it * 4096 + wid * 1024);
  }
  __syncthreads();

  for (int i = 0; i < ktpb; i++) {
    const int kt = kt0 + i;
    const int buf = i & 1, nbuf = buf ^ 1;
    char* As = smem + buf * 16384;
    char* Bs = smem + 32768 + buf * 16384;
    if (i < ktpb - 1) {
      #pragma unroll
      for (int it = 0; it < 4; it++) {
        int p = (it * 256 + tid) * 16;
        int e = p ^ (((p >> 7) & 7) << 4);
        int row = e >> 7, col = e & 127;
        gl_lds16(Ab + (size_t)row * 2048 + (kt + 1) * 128 + col,
                 smem + nbuf * 16384 + it * 4096 + wid * 1024);
        gl_lds16(Bb + (size_t)row * 2048 + (kt + 1) * 128 + col,
                 smem + 32768 + nbuf * 16384 + it * 4096 + wid * 1024);
      }
    }
    #pragma unroll
    for (int kc = 0; kc < 2; kc++) {
      bf16x8 af[4], bfr[4];
      #pragma unroll
      for (int m = 0; m < 4; m++) {
        int row = wm * 64 + m * 16 + (lane & 15);
        int e = row * 128 + kc * 64 + ((lane >> 4) << 4);
        af[m] = *(const bf16x8*)(As + (e ^ ((row & 7) << 4)));
      }
      #pragma unroll
      for (int n = 0; n < 4; n++) {
        int row = wn * 64 + n * 16 + (lane & 15);
        int e = row * 128 + kc * 64 + ((lane >> 4) << 4);
        bfr[n] = *(const bf16x8*)(Bs + (e ^ ((row & 7) << 4)));
      }
      #pragma unroll
      for (int m = 0; m < 4; m++)
        #pragma unroll
        for (int n = 0; n < 4; n++)
          acc[m][n] = __builtin_amdgcn_mfma_f32_16x16x32_bf16(af[m], bfr[n], acc[m][n], 0, 0, 0);
    }
    __syncthreads();
  }
  float bv[4];
  #pragma unroll
  for (int n = 0; n < 4; n++) bv[n] = bias[nb * 128 + wn * 64 + n * 16 + (lane & 15)];
  #pragma unroll
  for (int m = 0; m < 4; m++)
    #pragma unroll
    for (int j = 0; j < 4; j++) {
      int r = wm * 64 + m * 16 + ((lane >> 4) << 2) + j;
      int gr = drow[r];
      float* orow = Out + (size_t)gr * 1024 + nb * 128 + wn * 64;
      #pragma unroll
      for (int n = 0; n < 4; n++)
        orow[n * 16 + (lane & 15)] = acc[m][n][j] + bv[n];
    }
}

// ---------------- launch ----------------
extern "C" void kernel_launch(void* const* d_in, const int* in_sizes, int n_in,
                              void* d_out, int out_size, void* d_ws, size_t ws_size,
                              hipStream_t stream) {
  (void)in_sizes; (void)n_in; (void)out_size;
  const float* x = (const float*)d_in[0];
  const float* wqkv0 = (const float*)d_in[3];
  const float* bqkv0 = (const float*)d_in[4];
  const float* wo0 = (const float*)d_in[5];
  const float* bo0 = (const float*)d_in[6];
  const float* wqkv1 = (const float*)d_in[7];
  const float* bqkv1 = (const float*)d_in[8];
  const float* wo1 = (const float*)d_in[9];
  const float* bo1 = (const float*)d_in[10];
  const float* wqkv2 = (const float*)d_in[11];
  const float* bqkv2 = (const float*)d_in[12];
  const float* wo2 = (const float*)d_in[13];
  const float* bo2 = (const float*)d_in[14];

  if (ws_size < 172032000ull) return;
  char* ws = (char*)d_ws;
  u16* xh    = (u16*)(ws + 65536);             // 29,360,128 B
  u16* wqkvt = (u16*)(ws + 29425664);          // 18,874,368 B
  u16* wot   = (u16*)(ws + 48300032);          //  6,291,456 B
  u16* qkv   = (u16*)(ws + 54591488);          // 88,080,384 B
  u16* opre  = (u16*)(ws + 142671872);         // 29,360,128 B
  float* out = (float*)d_out;

  wtrans_kernel<<<dim3(128, 32, 3), dim3(32, 8), 0, stream>>>(wqkv0, wqkv1, wqkv2,
                                                              wo0, wo1, wo2, wqkvt, wot);
  gather_kernel<<<14336, 256, 0, stream>>>(x, xh);
  qkv_gemm_kernel<<<672, 512, 0, stream>>>(xh, wqkvt, bqkv0, bqkv1, bqkv2, qkv);
  attn_kernel<<<dim3(8, 48), 512, 0, stream>>>(qkv, opre);
  out_gemm_kernel<<<dim3(112, 8), 256, 0, stream>>>(opre, wot, bo0, bo1, bo2, out);
}

// Round 20
// 270.746 us; speedup vs baseline: 1.0385x; 1.0385x over previous
//
#include <hip/hip_runtime.h>
#include <stdint.h>
#include <stddef.h>

typedef unsigned short u16;
typedef short bf16x8 __attribute__((ext_vector_type(8)));
typedef float f32x4 __attribute__((ext_vector_type(4)));
typedef float f32x16 __attribute__((ext_vector_type(16)));
typedef unsigned short ushort8v __attribute__((ext_vector_type(8)));
typedef int i32x2 __attribute__((ext_vector_type(2)));

#define LR 2048
#define LOG2E 1.44269504088896f

__device__ __forceinline__ u16 f2bf(float f) {
  unsigned u = __float_as_uint(f);
  unsigned r = u + 0x7fffu + ((u >> 16) & 1u);
  return (u16)(r >> 16);
}

__device__ __forceinline__ unsigned cvtpk(float lo, float hi) {
  unsigned r;
  asm("v_cvt_pk_bf16_f32 %0, %1, %2" : "=v"(r) : "v"(lo), "v"(hi));
  return r;
}

// v_permlane32_swap: vdst[32:63] <-> vsrc[0:31]
__device__ __forceinline__ void plswap(unsigned& a, unsigned& b) {
#if __has_builtin(__builtin_amdgcn_permlane32_swap)
  i32x2 r = __builtin_amdgcn_permlane32_swap((int)a, (int)b, false, false);
  a = (unsigned)r[0];
  b = (unsigned)r[1];
#else
  asm volatile("s_nop 1\n\tv_permlane32_swap_b32 %0, %1\n\ts_nop 1"
               : "+v"(a), "+v"(b));
#endif
}
__device__ __forceinline__ float xhalf_sum(float x) {
  unsigned a = __float_as_uint(x), b = __float_as_uint(x);
  plswap(a, b);
  return __uint_as_float(a) + __uint_as_float(b);
}

__device__ __forceinline__ void gl_lds16(const void* g, void* l) {
  __builtin_amdgcn_global_load_lds((__attribute__((address_space(1))) void*)g,
                                   (__attribute__((address_space(3))) void*)l,
                                   16, 0, 0);
}

// Closed-form Hilbert perm for this problem's segments (inlined, no kernel)
__device__ __forceinline__ int hilbert_perm(int idx) {
  int seg = (idx < 2048) ? 0 : (idx < 6144 ? 1 : 2);
  int segpos = (seg == 0) ? 0 : (seg == 1 ? 2048 : 6144);
  int L = 2048 << seg;
  int n = (seg == 2) ? 128 : 64;
  int t = idx - segpos;
  int d = (L == n * n) ? t : ((t < (L >> 1)) ? t : t + L);
  int x = 0, y = 0;
  for (int s = 1; s < n; s <<= 1) {
    int rx = 1 & (d >> 1);
    int ry = 1 & (d ^ rx);
    if (ry == 0) {
      if (rx == 1) { x = s - 1 - x; y = s - 1 - y; }
      int tmp = x; x = y; y = tmp;
    }
    x += s * rx; y += s * ry;
    d >>= 2;
  }
  return y * n + x;
}

// ---------------- fused prologue: weight transpose panels + x-row gather -----
// blocks [0,12288): wtrans (128 x 32 x 3 panels); [12288,26624): gather rows.
// Independent outputs (wqkvt/wot vs xh); both consumed by qkv_gemm.
__global__ void prep_kernel(const float* __restrict__ q0, const float* __restrict__ q1,
                            const float* __restrict__ q2, const float* __restrict__ o0,
                            const float* __restrict__ o1, const float* __restrict__ o2,
                            const float* __restrict__ x,
                            u16* __restrict__ dq, u16* __restrict__ dw,
                            u16* __restrict__ xh) {
  __shared__ float tl[32][33];
  const int b = blockIdx.x;
  const int tid = threadIdx.x;
  if (b < 12288) {
    // ---- wtrans panel ----
    const int bx = b & 127;
    const int ky = (b >> 7) & 31;
    const int seg = b >> 12;
    const int K = 1024;
    const int tx = tid & 31, ty = tid >> 5;  // 32 x 8
    const float* S;
    u16* D;
    int N, n0, do_remap;
    if (bx < 96) {
      S = (seg == 0) ? q0 : (seg == 1 ? q1 : q2);
      D = dq + (size_t)seg * K * 3072;
      N = 3072; n0 = bx * 32; do_remap = 0;
    } else {
      S = (seg == 0) ? o0 : (seg == 1 ? o1 : o2);
      D = dw + (size_t)seg * K * 1024;
      N = 1024; n0 = (bx - 96) * 32; do_remap = 1;
    }
    int k0 = ky * 32;
    #pragma unroll
    for (int i = 0; i < 4; i++)
      tl[ty + 8 * i][tx] = S[(size_t)(k0 + ty + 8 * i) * N + n0 + tx];
    __syncthreads();
    int kk = k0 + tx;
    if (do_remap) {
      int rate = 1 << seg;
      int h = kk >> 6;
      int h2 = (h & (rate - 1)) * (16 >> seg) + (h >> seg);
      kk = h2 * 64 + (kk & 63);
    }
    #pragma unroll
    for (int i = 0; i < 4; i++)
      D[(size_t)(n0 + ty + 8 * i) * K + kk] = f2bf(tl[tx][ty + 8 * i]);
  } else {
    // ---- gather row ----
    int rr = b - 12288;
    int seg = (rr < 2048) ? 0 : (rr < 6144 ? 1 : 2);
    int segpos = (seg == 0) ? 0 : (seg == 1 ? 2048 : 6144);
    int rate = 1 << seg;
    int rl = rr - segpos;
    int t = (rl & (LR - 1)) * rate + (rl >> 11);
    int orig = segpos + hilbert_perm(segpos + t);
    float4 v = *((const float4*)(x + (size_t)orig * 1024) + tid);
    ushort4 o;
    o.x = f2bf(v.x); o.y = f2bf(v.y); o.z = f2bf(v.z); o.w = f2bf(v.w);
    *((ushort4*)(xh + (size_t)rr * 1024) + tid) = o;
  }
}

// ---------------- QKV GEMM (R14-exact): 256x256 tile, 8 waves, BK=64, -------
// 128KB LDS dbuf, stage-early + single __syncthreads per K-step, XCD supertile.
__global__ __launch_bounds__(512, 2) void qkv_gemm_kernel(
    const u16* __restrict__ A, const u16* __restrict__ Bt,
    const float* __restrict__ b0, const float* __restrict__ b1,
    const float* __restrict__ b2, u16* __restrict__ C) {
  __shared__ char smem[131072];
  const int tid = threadIdx.x;
  const int lane = tid & 63, wid = tid >> 6;   // 8 waves
  const int wm = wid >> 2, wn = wid & 3;       // 2m x 4n, wave tile 128x64
  const int bid = blockIdx.x;                  // 672 = 8 xcd * (2 grp * 7 rb * 6 nb)
  const int xcd = bid & 7;
  const int idx = bid >> 3;
  const int grp = idx / 42;
  const int rem = idx % 42;
  const int rb = xcd * 7 + rem / 6;
  const int nb = grp * 6 + rem % 6;
  const int seg = (rb < 8) ? 0 : (rb < 24 ? 1 : 2);
  const float* bias = (seg == 0) ? b0 : (seg == 1 ? b1 : b2);
  const size_t arow0 = (size_t)rb * 256;
  const char* Ab = (const char*)(A + arow0 * 1024);
  const char* Bb = (const char*)(Bt + ((size_t)seg * 3072 + (size_t)nb * 256) * 1024);

  f32x4 acc[8][4] = {};

  #pragma unroll
  for (int it = 0; it < 4; it++) {
    int p = (it * 512 + tid) * 16;
    int e = p ^ (((p >> 7) & 7) << 4);
    int row = e >> 7, col = e & 127;
    gl_lds16(Ab + (size_t)row * 2048 + col, smem + it * 8192 + wid * 1024);
    gl_lds16(Bb + (size_t)row * 2048 + col, smem + 65536 + it * 8192 + wid * 1024);
  }
  __syncthreads();

  for (int kt = 0; kt < 16; kt++) {
    const int buf = kt & 1, nbuf = buf ^ 1;
    char* As = smem + buf * 32768;
    char* Bs = smem + 65536 + buf * 32768;
    if (kt < 15) {
      #pragma unroll
      for (int it = 0; it < 4; it++) {
        int p = (it * 512 + tid) * 16;
        int e = p ^ (((p >> 7) & 7) << 4);
        int row = e >> 7, col = e & 127;
        gl_lds16(Ab + (size_t)row * 2048 + (kt + 1) * 128 + col,
                 smem + nbuf * 32768 + it * 8192 + wid * 1024);
        gl_lds16(Bb + (size_t)row * 2048 + (kt + 1) * 128 + col,
                 smem + 65536 + nbuf * 32768 + it * 8192 + wid * 1024);
      }
    }
    #pragma unroll
    for (int kc = 0; kc < 2; kc++) {
      bf16x8 af[8], bfr[4];
      #pragma unroll
      for (int m = 0; m < 8; m++) {
        int row = wm * 128 + m * 16 + (lane & 15);
        int e = row * 128 + kc * 64 + ((lane >> 4) << 4);
        af[m] = *(const bf16x8*)(As + (e ^ ((row & 7) << 4)));
      }
      #pragma unroll
      for (int n = 0; n < 4; n++) {
        int row = wn * 64 + n * 16 + (lane & 15);
        int e = row * 128 + kc * 64 + ((lane >> 4) << 4);
        bfr[n] = *(const bf16x8*)(Bs + (e ^ ((row & 7) << 4)));
      }
      #pragma unroll
      for (int m = 0; m < 8; m++)
        #pragma unroll
        for (int n = 0; n < 4; n++)
          acc[m][n] = __builtin_amdgcn_mfma_f32_16x16x32_bf16(af[m], bfr[n], acc[m][n], 0, 0, 0);
    }
    __syncthreads();
  }

  float bv[4];
  #pragma unroll
  for (int n = 0; n < 4; n++) bv[n] = bias[nb * 256 + wn * 64 + n * 16 + (lane & 15)];
  #pragma unroll
  for (int pass = 0; pass < 2; pass++) {
    if (wm == pass) {
      #pragma unroll
      for (int m = 0; m < 8; m++)
        #pragma unroll
        for (int n = 0; n < 4; n++)
          #pragma unroll
          for (int j = 0; j < 4; j++) {
            int r = m * 16 + ((lane >> 4) << 2) + j;
            int c = wn * 64 + n * 16 + (lane & 15);
            *(u16*)(smem + r * 528 + c * 2) = f2bf(acc[m][n][j] + bv[n]);
          }
    }
    __syncthreads();
    #pragma unroll
    for (int it = 0; it < 8; it++) {
      int ci = it * 512 + tid;
      int row = ci >> 5, c16 = ci & 31;
      bf16x8 vv = *(const bf16x8*)(smem + row * 528 + c16 * 16);
      u16* crow = C + (arow0 + pass * 128 + row) * 3072 + nb * 256;
      *(bf16x8*)((char*)crow + c16 * 16) = vv;
    }
    if (pass == 0) __syncthreads();
  }
}

// ---------------- flash attention (R17-exact): STATIC-max softmax ------------
__global__ __launch_bounds__(256) void attn_kernel(const u16* __restrict__ qkv,
                                                   u16* __restrict__ opre) {
  __shared__ char smem[32768];
  const int tid = threadIdx.x;
  const int lane = tid & 63;
  const int wid = tid >> 6;
  const int l31 = lane & 31;
  const int hi = lane >> 5;
  const int by = blockIdx.y;
  const int seg = by >> 4, h = by & 15;
  const int segrow = (seg == 0) ? 0 : (seg == 1 ? 2048 : 6144);
  const int rate = 1 << seg;
  const int off = h & (rate - 1);
  const int base = segrow + off * LR;
  const int h_col = off * (16 >> seg) + (h >> seg);
  const int q0 = blockIdx.x * 128;
  const int qw = q0 + wid * 32;
  const char* qb = (const char*)qkv;

  const int vkey0 = 2 * (tid & 31);
  const int vd0 = (tid >> 5) * 8;

  #pragma unroll
  for (int it = 0; it < 2; it++) {
    int p = (it * 256 + tid) * 16;
    int e = p ^ (((p >> 7) & 7) << 4);
    int row = e >> 7, col = e & 127;
    gl_lds16(qb + (size_t)(base + row) * 6144 + 2048 + h * 128 + col,
             smem + it * 4096 + wid * 1024);
  }
  ushort8v v0r = *(const ushort8v*)(qb + (size_t)(base + vkey0) * 6144 + 4096 + h * 128 + vd0 * 2);
  ushort8v v1r = *(const ushort8v*)(qb + (size_t)(base + vkey0 + 1) * 6144 + 4096 + h * 128 + vd0 * 2);
  bf16x8 qf[4];
  #pragma unroll
  for (int i2 = 0; i2 < 4; i2++)
    qf[i2] = *(const bf16x8*)(qb + (size_t)(base + qw + l31) * 6144 + h * 128 + i2 * 32 + hi * 16);
  #pragma unroll
  for (int dd = 0; dd < 8; dd++) {
    int d = vd0 + dd;
    unsigned val = (unsigned)(u16)v0r[dd] | ((unsigned)(u16)v1r[dd] << 16);
    int addr = d * 128 + vkey0 * 2;
    *(unsigned*)(smem + 16384 + (addr ^ ((d & 7) << 4))) = val;
  }
  __syncthreads();

  float Lrun = 0.f;
  f32x16 accO0 = {}, accO1 = {};
  const float K1 = 0.125f * LOG2E;
  const float C2 = 4.0f * LOG2E;

  for (int kt = 0; kt < 32; kt++) {
    const int cur = kt & 1;
    const int nxt = cur ^ 1;
    char* Ks  = smem + (cur << 13);
    char* Vt  = smem + 16384 + (cur << 13);
    char* Ksn = smem + (nxt << 13);
    char* Vtn = smem + 16384 + (nxt << 13);
    ushort8v nv0, nv1;
    if (kt < 31) {
      #pragma unroll
      for (int it = 0; it < 2; it++) {
        int p = (it * 256 + tid) * 16;
        int e = p ^ (((p >> 7) & 7) << 4);
        int row = e >> 7, col = e & 127;
        gl_lds16(qb + (size_t)(base + (kt + 1) * 64 + row) * 6144 + 2048 + h * 128 + col,
                 Ksn + it * 4096 + wid * 1024);
      }
      nv0 = *(const ushort8v*)(qb + (size_t)(base + (kt + 1) * 64 + vkey0) * 6144 + 4096 + h * 128 + vd0 * 2);
      nv1 = *(const ushort8v*)(qb + (size_t)(base + (kt + 1) * 64 + vkey0 + 1) * 6144 + 4096 + h * 128 + vd0 * 2);
    }
    #pragma unroll
    for (int s = 0; s < 2; s++) {
      f32x16 sacc = {};
      __builtin_amdgcn_s_setprio(1);
      #pragma unroll
      for (int i2 = 0; i2 < 4; i2++) {
        int row = s * 32 + l31;
        int addr = (row * 128 + i2 * 32 + hi * 16) ^ ((row & 7) << 4);
        bf16x8 kf = *(const bf16x8*)(Ks + addr);
        sacc = __builtin_amdgcn_mfma_f32_32x32x16_bf16(kf, qf[i2], sacc, 0, 0, 0);
      }
      __builtin_amdgcn_s_setprio(0);
      #pragma unroll
      for (int r = 0; r < 16; r++) sacc[r] = exp2f(sacc[r] * K1 - C2);
      float s8[8];
      #pragma unroll
      for (int t = 0; t < 8; t++) s8[t] = sacc[2 * t] + sacc[2 * t + 1];
      float sm = (((s8[0] + s8[1]) + (s8[2] + s8[3])) + ((s8[4] + s8[5]) + (s8[6] + s8[7])));
      Lrun += xhalf_sum(sm);
      unsigned w[8];
      #pragma unroll
      for (int t = 0; t < 8; t++) w[t] = cvtpk(sacc[2 * t], sacc[2 * t + 1]);
      plswap(w[0], w[2]); plswap(w[1], w[3]);
      plswap(w[4], w[6]); plswap(w[5], w[7]);
      union PU { unsigned u[4]; bf16x8 v; };
      PU pu0, pu1;
      pu0.u[0] = w[0]; pu0.u[1] = w[1]; pu0.u[2] = w[2]; pu0.u[3] = w[3];
      pu1.u[0] = w[4]; pu1.u[1] = w[5]; pu1.u[2] = w[6]; pu1.u[3] = w[7];
      __builtin_amdgcn_s_setprio(1);
      #pragma unroll
      for (int j = 0; j < 2; j++) {
        bf16x8 pa = (j == 0) ? pu0.v : pu1.v;
        #pragma unroll
        for (int dt = 0; dt < 2; dt++) {
          int d = dt * 32 + l31;
          int addr = (d * 128 + s * 64 + j * 32 + hi * 16) ^ ((d & 7) << 4);
          bf16x8 vf = *(const bf16x8*)(Vt + addr);
          if (dt == 0) accO0 = __builtin_amdgcn_mfma_f32_32x32x16_bf16(pa, vf, accO0, 0, 0, 0);
          else         accO1 = __builtin_amdgcn_mfma_f32_32x32x16_bf16(pa, vf, accO1, 0, 0, 0);
        }
      }
      __builtin_amdgcn_s_setprio(0);
    }
    if (kt < 31) {
      #pragma unroll
      for (int dd = 0; dd < 8; dd++) {
        int d = vd0 + dd;
        unsigned val = (unsigned)(u16)nv0[dd] | ((unsigned)(u16)nv1[dd] << 16);
        int addr = d * 128 + vkey0 * 2;
        *(unsigned*)(Vtn + (addr ^ ((d & 7) << 4))) = val;
      }
    }
    __syncthreads();
  }

  float invL = 1.0f / Lrun;
  #pragma unroll
  for (int r = 0; r < 16; r++) {
    int qrow = (r & 3) + 8 * (r >> 2) + 4 * hi;
    float li = __shfl(invL, qrow);
    int qloc = wid * 32 + qrow;
    int a0 = (qloc * 128 + l31 * 2) ^ ((qrow & 7) << 4);
    int a1 = (qloc * 128 + 64 + l31 * 2) ^ ((qrow & 7) << 4);
    *(u16*)(smem + a0) = f2bf(accO0[r] * li);
    *(u16*)(smem + a1) = f2bf(accO1[r] * li);
  }
  __syncthreads();
  #pragma unroll
  for (int it = 0; it < 4; it++) {
    int idx = it * 256 + tid;
    int row = idx >> 3, c16 = idx & 7;
    int a = (row * 128 + c16 * 16) ^ ((row & 7) << 4);
    bf16x8 vv = *(const bf16x8*)(smem + a);
    *(bf16x8*)((char*)(opre + (size_t)(base + q0 + row) * 1024 + h_col * 64) + c16 * 16) = vv;
  }
}

// ---------------- OUT GEMM (2-phase dbuf): residue-sparse x Wo^T -> f32 ------
__global__ __launch_bounds__(256) void out_gemm_kernel(
    const u16* __restrict__ A, const u16* __restrict__ Bt,
    const float* __restrict__ b0, const float* __restrict__ b1,
    const float* __restrict__ b2, float* __restrict__ Out) {
  __shared__ char smem[65536];
  __shared__ int drow[128];
  const int tid = threadIdx.x;
  const int lane = tid & 63, wid = tid >> 6;
  const int wm = wid >> 1, wn = wid & 1;
  const int rb = blockIdx.x, nb = blockIdx.y;
  const int seg = (rb < 16) ? 0 : (rb < 48 ? 1 : 2);
  const int segpos = (seg == 0) ? 0 : (seg == 1 ? 2048 : 6144);
  const int rate = 1 << seg;
  const float* bias = (seg == 0) ? b0 : (seg == 1 ? b1 : b2);
  const size_t arow0 = (size_t)rb * 128;
  const char* Ab = (const char*)(A + arow0 * 1024);
  const char* Bb = (const char*)(Bt + ((size_t)seg * 1024 + (size_t)nb * 128) * 1024);

  const int blk = (int)(arow0 - segpos) >> 11;
  const int ktpb = 16 >> seg;
  const int kt0 = blk * ktpb;

  f32x4 acc[4][4] = {};

  if (tid < 128) {
    int rl = (int)arow0 + tid - segpos;
    int t = (rl & (LR - 1)) * rate + (rl >> 11);
    drow[tid] = segpos + hilbert_perm(segpos + t);
  }

  #pragma unroll
  for (int it = 0; it < 4; it++) {
    int p = (it * 256 + tid) * 16;
    int e = p ^ (((p >> 7) & 7) << 4);
    int row = e >> 7, col = e & 127;
    gl_lds16(Ab + (size_t)row * 2048 + kt0 * 128 + col, smem + it * 4096 + wid * 1024);
    gl_lds16(Bb + (size_t)row * 2048 + kt0 * 128 + col, smem + 32768 + it * 4096 + wid * 1024);
  }
  __syncthreads();

  for (int i = 0; i < ktpb; i++) {
    const int kt = kt0 + i;
    const int buf = i & 1, nbuf = buf ^ 1;
    char* As = smem + buf * 16384;
    char* Bs = smem + 32768 + buf * 16384;
    if (i < ktpb - 1) {
      #pragma unroll
      for (int it = 0; it < 4; it++) {
        int p = (it * 256 + tid) * 16;
        int e = p ^ (((p >> 7) & 7) << 4);
        int row = e >> 7, col = e & 127;
        gl_lds16(Ab + (size_t)row * 2048 + (kt + 1) * 128 + col,
                 smem + nbuf * 16384 + it * 4096 + wid * 1024);
        gl_lds16(Bb + (size_t)row * 2048 + (kt + 1) * 128 + col,
                 smem + 32768 + nbuf * 16384 + it * 4096 + wid * 1024);
      }
    }
    #pragma unroll
    for (int kc = 0; kc < 2; kc++) {
      bf16x8 af[4], bfr[4];
      #pragma unroll
      for (int m = 0; m < 4; m++) {
        int row = wm * 64 + m * 16 + (lane & 15);
        int e = row * 128 + kc * 64 + ((lane >> 4) << 4);
        af[m] = *(const bf16x8*)(As + (e ^ ((row & 7) << 4)));
      }
      #pragma unroll
      for (int n = 0; n < 4; n++) {
        int row = wn * 64 + n * 16 + (lane & 15);
        int e = row * 128 + kc * 64 + ((lane >> 4) << 4);
        bfr[n] = *(const bf16x8*)(Bs + (e ^ ((row & 7) << 4)));
      }
      #pragma unroll
      for (int m = 0; m < 4; m++)
        #pragma unroll
        for (int n = 0; n < 4; n++)
          acc[m][n] = __builtin_amdgcn_mfma_f32_16x16x32_bf16(af[m], bfr[n], acc[m][n], 0, 0, 0);
    }
    __syncthreads();
  }
  float bv[4];
  #pragma unroll
  for (int n = 0; n < 4; n++) bv[n] = bias[nb * 128 + wn * 64 + n * 16 + (lane & 15)];
  #pragma unroll
  for (int m = 0; m < 4; m++)
    #pragma unroll
    for (int j = 0; j < 4; j++) {
      int r = wm * 64 + m * 16 + ((lane >> 4) << 2) + j;
      int gr = drow[r];
      float* orow = Out + (size_t)gr * 1024 + nb * 128 + wn * 64;
      #pragma unroll
      for (int n = 0; n < 4; n++)
        orow[n * 16 + (lane & 15)] = acc[m][n][j] + bv[n];
    }
}

// ---------------- launch ----------------
extern "C" void kernel_launch(void* const* d_in, const int* in_sizes, int n_in,
                              void* d_out, int out_size, void* d_ws, size_t ws_size,
                              hipStream_t stream) {
  (void)in_sizes; (void)n_in; (void)out_size;
  const float* x = (const float*)d_in[0];
  const float* wqkv0 = (const float*)d_in[3];
  const float* bqkv0 = (const float*)d_in[4];
  const float* wo0 = (const float*)d_in[5];
  const float* bo0 = (const float*)d_in[6];
  const float* wqkv1 = (const float*)d_in[7];
  const float* bqkv1 = (const float*)d_in[8];
  const float* wo1 = (const float*)d_in[9];
  const float* bo1 = (const float*)d_in[10];
  const float* wqkv2 = (const float*)d_in[11];
  const float* bqkv2 = (const float*)d_in[12];
  const float* wo2 = (const float*)d_in[13];
  const float* bo2 = (const float*)d_in[14];

  if (ws_size < 172032000ull) return;
  char* ws = (char*)d_ws;
  u16* xh    = (u16*)(ws + 65536);             // 29,360,128 B
  u16* wqkvt = (u16*)(ws + 29425664);          // 18,874,368 B
  u16* wot   = (u16*)(ws + 48300032);          //  6,291,456 B
  u16* qkv   = (u16*)(ws + 54591488);          // 88,080,384 B
  u16* opre  = (u16*)(ws + 142671872);         // 29,360,128 B
  float* out = (float*)d_out;

  prep_kernel<<<26624, 256, 0, stream>>>(wqkv0, wqkv1, wqkv2, wo0, wo1, wo2,
                                         x, wqkvt, wot, xh);
  qkv_gemm_kernel<<<672, 512, 0, stream>>>(xh, wqkvt, bqkv0, bqkv1, bqkv2, qkv);
  attn_kernel<<<dim3(16, 48), 256, 0, stream>>>(qkv, opre);
  out_gemm_kernel<<<dim3(112, 8), 256, 0, stream>>>(opre, wot, bo0, bo1, bo2, out);
}